// Round 16
// baseline (107.045 us; speedup 1.0000x reference)
//
#include <hip/hip_runtime.h>

#define NBATCH  131072
#define THREADS 256            // 4 fully independent waves per block
#define WPB     4
#define BPW     8              // batches per wave
#define NBLOCKS (NBATCH / (WPB * BPW))   // 4096

typedef __attribute__((ext_vector_type(8))) _Float16 half8;
typedef __attribute__((ext_vector_type(4))) float f32x4;

// Per-wave LDS slice: xT/y f16 [8 b][15 p][64B], batch stride 976B (61x16B units)
//                     stage-3 reuses [0, 7040) as out staging f32 [8][220]
#define XT_BS 976
#define SLICE 7808
#define SMEM_BYTES (WPB * SLICE)

// d_ws layout (bytes) — identical to v12/v13/v14:
#define WF1_OFF 2048
#define WF2_OFF 14336
#define SH1_OFF 26624
#define SH2_OFF 26880

static __device__ __forceinline__ unsigned short f2h(float f) {
    return __builtin_bit_cast(unsigned short, (_Float16)f);   // RNE
}
static __device__ __forceinline__ unsigned int pack2h(float a, float b) {
    return (unsigned int)f2h(a) | ((unsigned int)f2h(b) << 16);
}
static __device__ __forceinline__ unsigned int pkrtz(float a, float b) {
    __fp16 __attribute__((ext_vector_type(2))) h =
        __builtin_amdgcn_cvt_pkrtz(a, b);                     // 1 VALU op, RTZ
    return __builtin_bit_cast(unsigned int, h);
}
static __device__ __forceinline__ half8 splat8(float s) {
    const _Float16 h = (_Float16)s;
    half8 v;
    #pragma unroll
    for (int j = 0; j < 8; ++j) v[j] = h;
    return v;
}
// wave-local LDS fence (no cross-wave barrier); sched_barrier per rule #18
static __device__ __forceinline__ void wave_fence() {
    asm volatile("s_waitcnt lgkmcnt(0)" ::: "memory");
    __builtin_amdgcn_sched_barrier(0);
}

// ================= prep kernel: fold BN, pack per-lane fragments into d_ws ==============
__global__ __launch_bounds__(64, 1)
void peptide_prep(const float* __restrict__ w0,
                  const float* __restrict__ w1, const float* __restrict__ cb1,
                  const float* __restrict__ g1, const float* __restrict__ bt1,
                  const float* __restrict__ mn1, const float* __restrict__ vr1,
                  const float* __restrict__ w2, const float* __restrict__ cb2,
                  const float* __restrict__ g2, const float* __restrict__ bt2,
                  const float* __restrict__ mn2, const float* __restrict__ vr2,
                  char* __restrict__ ws)
{
    const int lane = threadIdx.x;
    const int col = lane & 15, g = lane >> 4;
    uint4* wf0 = (uint4*)ws;
    uint4* wf1 = (uint4*)(ws + WF1_OFF);
    uint4* wf2 = (uint4*)(ws + WF2_OFF);
    float* sh1 = (float*)(ws + SH1_OFF);
    float* sh2 = (float*)(ws + SH2_OFF);

    // conv0 fragments, chan0(mt,row) = 8*(row>>2) + 4*mt + (row&3)
    #pragma unroll
    for (int mt = 0; mt < 2; ++mt) {
        const int oc = 8*(col>>2) + 4*mt + (col&3);
        half8 fh;
        #pragma unroll
        for (int j = 0; j < 8; ++j) {
            const int c = 8 * g + j;
            fh[j] = (c < 21) ? (_Float16)w0[oc * 21 + c] : (_Float16)0.f;
        }
        wf0[mt * 64 + lane] = __builtin_bit_cast(uint4, fh);
    }
    // conv1 fragments, bn1 folded; chan1 = 32H + 8(col>>2) + 4t + (col&3)
    #pragma unroll
    for (int H = 0; H < 2; ++H)
    #pragma unroll
    for (int t = 0; t < 2; ++t) {
        const int o = 32*H + 8*(col>>2) + 4*t + (col&3);
        const float iva = g1[o] * rsqrtf(vr1[o] + 1e-5f);
        #pragma unroll
        for (int s = 0; s < 3; ++s) {
            half8 fh;
            #pragma unroll
            for (int j = 0; j < 8; ++j)
                fh[j] = (_Float16)(w1[o*96 + g*24 + j*3 + s] * iva);
            wf1[((H*2 + t)*3 + s)*64 + lane] = __builtin_bit_cast(uint4, fh);
        }
    }
    // conv2 fragments, bn2 folded, zero for o >= 20
    #pragma unroll
    for (int MT = 0; MT < 2; ++MT) {
        const int o = MT * 16 + col;
        const float iva = (o < 20) ? g2[o] * rsqrtf(vr2[o] + 1e-5f) : 0.f;
        #pragma unroll
        for (int hh = 0; hh < 2; ++hh)
        #pragma unroll
        for (int tap = 0; tap < 3; ++tap) {
            half8 fh;
            #pragma unroll
            for (int j = 0; j < 8; ++j)
                fh[j] = (o < 20) ? (_Float16)(w2[o*192 + hh*96 + g*24 + j*3 + tap] * iva)
                                 : (_Float16)0.f;
            wf2[((MT*2 + hh)*3 + tap)*64 + lane] = __builtin_bit_cast(uint4, fh);
        }
    }
    if (col == 0) {
        #pragma unroll
        for (int k = 0; k < 16; ++k) {
            const int H = k >> 3, t = (k >> 2) & 1, r = k & 3;
            const int o = 32*H + 8*g + 4*t + r;
            const float iva = g1[o] * rsqrtf(vr1[o] + 1e-5f);
            sh1[g*16 + k] = bt1[o] + (cb1[o] - mn1[o]) * iva;
        }
        #pragma unroll
        for (int k = 0; k < 8; ++k) {
            const int MT = k >> 2, r = k & 3;
            const int oc = MT*16 + 4*g + r;
            if (oc < 20) {
                const float iva = g2[oc] * rsqrtf(vr2[oc] + 1e-5f);
                sh2[g*8 + k] = bt2[oc] + (cb2[oc] - mn2[oc]) * iva;
            } else sh2[g*8 + k] = 0.f;
        }
    }
}

static __device__ __forceinline__ void write_row(char* sw, int b, int p,
                                                 const float (&v)[21]) {
    uint4 d0, d1, d2, d3;
    d0.x = pkrtz(v[0],  v[1]);  d0.y = pkrtz(v[2],  v[3]);
    d0.z = pkrtz(v[4],  v[5]);  d0.w = pkrtz(v[6],  v[7]);
    d1.x = pkrtz(v[8],  v[9]);  d1.y = pkrtz(v[10], v[11]);
    d1.z = pkrtz(v[12], v[13]); d1.w = pkrtz(v[14], v[15]);
    d2.x = pkrtz(v[16], v[17]); d2.y = pkrtz(v[18], v[19]);
    d2.z = pkrtz(v[20], 0.f);   d2.w = 0u;
    d3.x = 0u; d3.y = 0u; d3.z = 0u; d3.w = 0u;
    char* dst = sw + b * XT_BS + p * 64;
    *(uint4*)(dst)      = d0;
    *(uint4*)(dst + 16) = d1;
    *(uint4*)(dst + 32) = d2;
    *(uint4*)(dst + 48) = d3;
}

__global__ __launch_bounds__(THREADS, 3)
void peptide_v15(const float* __restrict__ x,
                 const float* __restrict__ attw,   // [15][32]
                 const float* __restrict__ attb,   // [15]
                 const char*  __restrict__ ws,
                 float* __restrict__ out)          // [B][20][11]
{
    __shared__ __align__(16) char smem[SMEM_BYTES];
    const int tid  = threadIdx.x;
    const int lane = tid & 63;
    const int wv   = tid >> 6;          // 0..3, fully independent waves
    const int col  = lane & 15;
    const int g    = lane >> 4;
    const int b    = col >> 1;          // batch within wave (0..7)
    const int ph   = col & 1;           // position half
    char* sw = smem + wv * SLICE;       // this wave's private LDS slice

    // ---- gather-transpose: lane = (batch, position-pair), 21 dwordx2 each ----
    {
        const float* xg = x + ((size_t)blockIdx.x * (WPB*BPW) + wv * BPW) * 315;
        const int gb = lane >> 3;
        const int pr = lane & 7;
        const bool lastp = (pr == 7);
        const int off0 = lastp ? 13 : 2 * pr;
        float lo[21], hi[21];
        #pragma unroll
        for (int c = 0; c < 21; ++c) {
            float2 v2 = *(const float2*)(xg + gb * 315 + c * 15 + off0);
            lo[c] = v2.x; hi[c] = v2.y;
        }
        if (!lastp) write_row(sw, gb, 2 * pr, lo);
        write_row(sw, gb, lastp ? 14 : 2 * pr + 1, hi);
    }
    wave_fence();

    // ---- conv0: 8 steps, column (b,ph) handles position p = 8*ph + i ----
    half8 af0a, af0b;
    {
        const uint4* wf0 = (const uint4*)ws;
        af0a = __builtin_bit_cast(half8, wf0[lane]);
        af0b = __builtin_bit_cast(half8, wf0[64 + lane]);
    }
    half8 hqs[8];
    float lg[8];
    #pragma unroll
    for (int i = 0; i < 8; ++i) {
        const int p  = ph * 8 + i;
        const int pe = (p > 14) ? 14 : p;          // ph1 i=7 -> dup row, discarded
        half8 bf = *(const half8*)(sw + b * XT_BS + pe * 64 + g * 16);
        const f32x4 z = {0.f, 0.f, 0.f, 0.f};
        f32x4 h0 = __builtin_amdgcn_mfma_f32_16x16x32_f16(af0a, bf, z, 0, 0, 0);
        f32x4 h1 = __builtin_amdgcn_mfma_f32_16x16x32_f16(af0b, bf, z, 0, 0, 0);
        float4 a0 = *(const float4*)(attw + pe * 32 + 8 * g);
        float4 a1 = *(const float4*)(attw + pe * 32 + 8 * g + 4);
        float lp = h0[0] * a0.x;
        lp = fmaf(h0[1], a0.y, lp); lp = fmaf(h0[2], a0.z, lp);
        lp = fmaf(h0[3], a0.w, lp); lp = fmaf(h1[0], a1.x, lp);
        lp = fmaf(h1[1], a1.y, lp); lp = fmaf(h1[2], a1.z, lp);
        lp = fmaf(h1[3], a1.w, lp);
        lp += __shfl_xor(lp, 16, 64);              // reduce over g
        lp += __shfl_xor(lp, 32, 64);
        lg[i] = lp + attb[pe];
        uint4 u;
        u.x = pack2h(h0[0], h0[1]); u.y = pack2h(h0[2], h0[3]);
        u.z = pack2h(h1[0], h1[1]); u.w = pack2h(h1[2], h1[3]);
        hqs[i] = __builtin_bit_cast(half8, u);     // channels 8g..8g+7 of (b, p)
    }

    // ---- softmax: partner logits via shfl lane^1, all-register ----
    {
        float plg[8];
        #pragma unroll
        for (int i = 0; i < 8; ++i) plg[i] = __shfl_xor(lg[i], 1, 64);
        float l15[15];
        #pragma unroll
        for (int p = 0; p < 15; ++p)
            l15[p] = (p < 8) ? (ph ? plg[p] : lg[p])
                             : (ph ? lg[p - 8] : plg[p - 8]);
        float mA = fmaxf(fmaxf(fmaxf(l15[0],l15[1]), fmaxf(l15[2],l15[3])),
                         fmaxf(fmaxf(l15[4],l15[5]), fmaxf(l15[6],l15[7])));
        float mB = fmaxf(fmaxf(fmaxf(l15[8],l15[9]), fmaxf(l15[10],l15[11])),
                         fmaxf(fmaxf(l15[12],l15[13]), l15[14]));
        const float mx = fmaxf(mA, mB);
        float e[15];
        #pragma unroll
        for (int l = 0; l < 15; ++l) e[l] = __expf(l15[l] - mx);
        float sA = ((e[0]+e[1]) + (e[2]+e[3])) + ((e[4]+e[5]) + (e[6]+e[7]));
        float sB = ((e[8]+e[9]) + (e[10]+e[11])) + ((e[12]+e[13]) + e[14]);
        const float inv = 1.f / (sA + sB);
        #pragma unroll
        for (int i = 0; i < 8; ++i) {
            const int phi = (8 + i > 14) ? 14 : 8 + i;
            const float sc = (ph ? e[phi] : e[i]) * inv;   // static indices both arms
            hqs[i] = hqs[i] * splat8(sc);                   // v_pk_mul_f16
        }
    }

    // ---- y -> LDS (own rows only; ph1 i=7 suppressed) ----
    #pragma unroll
    for (int i = 0; i < 8; ++i) {
        if (i < 7) {
            *(uint4*)(sw + b * XT_BS + (ph * 8 + i) * 64 + g * 16) =
                __builtin_bit_cast(uint4, hqs[i]);
        } else if (ph == 0) {
            *(uint4*)(sw + b * XT_BS + 7 * 64 + g * 16) =
                __builtin_bit_cast(uint4, hqs[7]);
        }
    }
    wave_fence();

    // ---- conv1: rows rbase..rbase+7, rbase = 6*ph (rows 6,7 computed by both ----
    // ---- phases; no halo shfl, no rotate — fr is statically indexed by both)  ----
    half8 fr0[8], fr1[8];
    const int rbase = ph * 6;
    {
        const uint4* wf1 = (const uint4*)(ws + WF1_OFF);
        const float* sh1p = (const float*)(ws + SH1_OFF) + g * 16;
        #pragma unroll
        for (int H = 0; H < 2; ++H) {
            half8 afA[3], afB[3];
            #pragma unroll
            for (int s = 0; s < 3; ++s) {
                afA[s] = __builtin_bit_cast(half8, wf1[((H*2 + 0)*3 + s)*64 + lane]);
                afB[s] = __builtin_bit_cast(half8, wf1[((H*2 + 1)*3 + s)*64 + lane]);
            }
            float4 shv0 = *(const float4*)(sh1p + H*8);
            float4 shv1 = *(const float4*)(sh1p + H*8 + 4);
            half8 y3[3];
            y3[0] = *(const half8*)(sw + b*XT_BS + (rbase + 0)*64 + g*16);
            y3[1] = *(const half8*)(sw + b*XT_BS + (rbase + 1)*64 + g*16);
            #pragma unroll
            for (int i = 0; i < 8; ++i) {
                int rr = rbase + i + 2;
                rr = (rr > 14) ? 14 : rr;          // ph1 i=7 garbage row, never used
                y3[(i + 2) % 3] = *(const half8*)(sw + b*XT_BS + rr*64 + g*16);
                // acc-init = bn shifts (saves the epilogue adds)
                f32x4 a0 = {shv0.x, shv0.y, shv0.z, shv0.w};
                f32x4 a1 = {shv1.x, shv1.y, shv1.z, shv1.w};
                #pragma unroll
                for (int s = 0; s < 3; ++s) {
                    const half8 yy = y3[(i + s) % 3];
                    a0 = __builtin_amdgcn_mfma_f32_16x16x32_f16(afA[s], yy, a0, 0,0,0);
                    a1 = __builtin_amdgcn_mfma_f32_16x16x32_f16(afB[s], yy, a1, 0,0,0);
                }
                float z0[4], z1[4];
                #pragma unroll
                for (int r2 = 0; r2 < 4; ++r2) {
                    z0[r2] = fmaxf(a0[r2], 0.01f * a0[r2]);
                    z1[r2] = fmaxf(a1[r2], 0.01f * a1[r2]);
                }
                uint4 u;
                u.x = pack2h(z0[0], z0[1]); u.y = pack2h(z0[2], z0[3]);
                u.z = pack2h(z1[0], z1[1]); u.w = pack2h(z1[2], z1[3]);
                if (H == 0) fr0[i] = __builtin_bit_cast(half8, u);
                else        fr1[i] = __builtin_bit_cast(half8, u);
            }
            __builtin_amdgcn_sched_barrier(0);
        }
    }

    // ---- conv2: 2 MT sweeps x 6 steps; column position p = 6*ph + j; fr[j+tap] ----
    {
        float* sout = (float*)sw;             // staging f32 [8][220]
        const uint4* wf2 = (const uint4*)(ws + WF2_OFF);
        #pragma unroll
        for (int MT = 0; MT < 2; ++MT) {
            half8 af3[6];
            #pragma unroll
            for (int hh = 0; hh < 2; ++hh)
            #pragma unroll
            for (int tap = 0; tap < 3; ++tap)
                af3[tap*2 + hh] =
                    __builtin_bit_cast(half8, wf2[((MT*2 + hh)*3 + tap)*64 + lane]);
            float4 shv = *(const float4*)((const float*)(ws + SH2_OFF) + g*8 + MT*4);
            #pragma unroll
            for (int j = 0; j < 6; ++j) {
                f32x4 acc = {shv.x, shv.y, shv.z, shv.w};   // acc-init = bn2 shifts
                #pragma unroll
                for (int s = 0; s < 6; ++s) {
                    const int tap = s >> 1, hh = s & 1;
                    const half8 bb = hh ? fr1[j + tap] : fr0[j + tap];
                    acc = __builtin_amdgcn_mfma_f32_16x16x32_f16(af3[s], bb, acc, 0,0,0);
                }
                const int p = ph ? 6 + j : j;
                if (j < 5 || ph == 0) {       // ph1 j=5 (p=11) is garbage
                    #pragma unroll
                    for (int r = 0; r < 4; ++r) {
                        const int oc = MT*16 + 4*g + r;
                        if (oc < 20) {
                            float t0 = fmaxf(acc[r], 0.01f * acc[r]);
                            sout[b*220 + oc*11 + p] = t0;
                        }
                    }
                }
            }
            __builtin_amdgcn_sched_barrier(0);
        }
    }
    wave_fence();

    // ---- gap-free coalesced copy-out: 8 x 220 dw = one 7040 B span per wave ----
    {
        float* ob = out + ((size_t)blockIdx.x * (WPB*BPW) + wv * BPW) * 220;
        const float* sf = (const float*)sw;
        #pragma unroll
        for (int it = 0; it < 7; ++it) {
            const int u = it * 64 + lane;     // 16B unit
            if (u < 440) {
                f32x4 v = *(const f32x4*)(sf + u * 4);
                *(f32x4*)(ob + u * 4) = v;
            }
        }
    }
}

extern "C" void kernel_launch(void* const* d_in, const int* in_sizes, int n_in,
                              void* d_out, int out_size, void* d_ws, size_t ws_size,
                              hipStream_t stream) {
    const float* x    = (const float*)d_in[0];
    const float* w0   = (const float*)d_in[1];
    const float* attw = (const float*)d_in[2];
    const float* attb = (const float*)d_in[3];
    const float* w1   = (const float*)d_in[4];
    const float* cb1  = (const float*)d_in[5];
    const float* g1   = (const float*)d_in[6];
    const float* bt1  = (const float*)d_in[7];
    const float* mn1  = (const float*)d_in[8];
    const float* vr1  = (const float*)d_in[9];
    const float* w2   = (const float*)d_in[10];
    const float* cb2  = (const float*)d_in[11];
    const float* g2   = (const float*)d_in[12];
    const float* bt2  = (const float*)d_in[13];
    const float* mn2  = (const float*)d_in[14];
    const float* vr2  = (const float*)d_in[15];

    hipLaunchKernelGGL(peptide_prep, dim3(1), dim3(64), 0, stream,
                       w0, w1, cb1, g1, bt1, mn1, vr1,
                       w2, cb2, g2, bt2, mn2, vr2, (char*)d_ws);
    hipLaunchKernelGGL(peptide_v15, dim3(NBLOCKS), dim3(THREADS), 0, stream,
                       x, attw, attb, (const char*)d_ws, (float*)d_out);
}

// Round 17
// 96.392 us; speedup vs baseline: 1.1105x; 1.1105x over previous
//
#include <hip/hip_runtime.h>

#define NBATCH  131072
#define THREADS 128
#define BPB     16
#define NBLOCKS (NBATCH / BPB)     // 8192

typedef __attribute__((ext_vector_type(8))) _Float16 half8;
typedef __attribute__((ext_vector_type(4))) float f32x4;

// LDS (bytes): sxT f16 [16 b][15 p][80B: 64B = ch 0..31 (21 data + 11 zero), 16B pad]
//              conv0 writes y in place; stage3 reuses [0,14080) as out f32 [16][220]
//  [19200, 20480):  lbuf f32 [16][20]  logit exchange
#define Y_RS 80
#define Y_BS 1200
#define LB_OFF 19200
#define SMEM_BYTES 20480
#define OUT_SDW 220

// d_ws layout (bytes):
#define WF1_OFF 2048
#define WF2_OFF 14336
#define SH1_OFF 26624
#define SH2_OFF 26880

static __device__ __forceinline__ unsigned short f2h(float f) {
    return __builtin_bit_cast(unsigned short, (_Float16)f);   // RNE
}
static __device__ __forceinline__ unsigned int pack2h(float a, float b) {
    return (unsigned int)f2h(a) | ((unsigned int)f2h(b) << 16);
}
static __device__ __forceinline__ unsigned int pkrtz(float a, float b) {
    __fp16 __attribute__((ext_vector_type(2))) h =
        __builtin_amdgcn_cvt_pkrtz(a, b);                     // 1 VALU op, RTZ
    return __builtin_bit_cast(unsigned int, h);
}
static __device__ __forceinline__ half8 splat8(float s) {
    const _Float16 h = (_Float16)s;
    half8 v;
    #pragma unroll
    for (int j = 0; j < 8; ++j) v[j] = h;
    return v;
}

// ================= prep kernel: fold BN, pack per-lane fragments into d_ws ==============
__global__ __launch_bounds__(64, 1)
void peptide_prep(const float* __restrict__ w0,
                  const float* __restrict__ w1, const float* __restrict__ cb1,
                  const float* __restrict__ g1, const float* __restrict__ bt1,
                  const float* __restrict__ mn1, const float* __restrict__ vr1,
                  const float* __restrict__ w2, const float* __restrict__ cb2,
                  const float* __restrict__ g2, const float* __restrict__ bt2,
                  const float* __restrict__ mn2, const float* __restrict__ vr2,
                  char* __restrict__ ws)
{
    const int lane = threadIdx.x;
    const int col = lane & 15, g = lane >> 4;
    uint4* wf0 = (uint4*)ws;
    uint4* wf1 = (uint4*)(ws + WF1_OFF);
    uint4* wf2 = (uint4*)(ws + WF2_OFF);
    float* sh1 = (float*)(ws + SH1_OFF);
    float* sh2 = (float*)(ws + SH2_OFF);

    // conv0 fragments
    #pragma unroll
    for (int mt = 0; mt < 2; ++mt) {
        const int o = mt * 16 + col;
        half8 fh;
        #pragma unroll
        for (int j = 0; j < 8; ++j) {
            const int c = 8 * g + j;
            fh[j] = (c < 21) ? (_Float16)w0[o * 21 + c] : (_Float16)0.f;
        }
        wf0[mt * 64 + lane] = __builtin_bit_cast(uint4, fh);
    }
    // conv1 fragments, bn1 scale folded; permuted channel o = 32H + 8(col>>2) + 4t + (col&3)
    #pragma unroll
    for (int H = 0; H < 2; ++H)
    #pragma unroll
    for (int t = 0; t < 2; ++t) {
        const int o = 32*H + 8*(col>>2) + 4*t + (col&3);
        const float iva = g1[o] * rsqrtf(vr1[o] + 1e-5f);
        #pragma unroll
        for (int s = 0; s < 3; ++s) {
            half8 fh;
            #pragma unroll
            for (int j = 0; j < 8; ++j)
                fh[j] = (_Float16)(w1[o*96 + g*24 + j*3 + s] * iva);
            wf1[((H*2 + t)*3 + s)*64 + lane] = __builtin_bit_cast(uint4, fh);
        }
    }
    // conv2 fragments, bn2 folded, zero for o >= 20
    #pragma unroll
    for (int MT = 0; MT < 2; ++MT) {
        const int o = MT * 16 + col;
        const float iva = (o < 20) ? g2[o] * rsqrtf(vr2[o] + 1e-5f) : 0.f;
        #pragma unroll
        for (int hh = 0; hh < 2; ++hh)
        #pragma unroll
        for (int tap = 0; tap < 3; ++tap) {
            half8 fh;
            #pragma unroll
            for (int j = 0; j < 8; ++j)
                fh[j] = (o < 20) ? (_Float16)(w2[o*192 + hh*96 + g*24 + j*3 + tap] * iva)
                                 : (_Float16)0.f;
            wf2[((MT*2 + hh)*3 + tap)*64 + lane] = __builtin_bit_cast(uint4, fh);
        }
    }
    // shift vectors (per g)
    if (col == 0) {
        #pragma unroll
        for (int k = 0; k < 16; ++k) {
            const int H = k >> 3, t = (k >> 2) & 1, r = k & 3;
            const int o = 32*H + 8*g + 4*t + r;
            const float iva = g1[o] * rsqrtf(vr1[o] + 1e-5f);
            sh1[g*16 + k] = bt1[o] + (cb1[o] - mn1[o]) * iva;
        }
        #pragma unroll
        for (int k = 0; k < 8; ++k) {
            const int MT = k >> 2, r = k & 3;
            const int oc = MT*16 + 4*g + r;
            if (oc < 20) {
                const float iva = g2[oc] * rsqrtf(vr2[oc] + 1e-5f);
                sh2[g*8 + k] = bt2[oc] + (cb2[oc] - mn2[oc]) * iva;
            } else sh2[g*8 + k] = 0.f;
        }
    }
}

// ---- conv0 via MFMA + attention softmax; h packed f16; y in-place to sxT ----
template<int P0, int NP>
__device__ __forceinline__ void conv0_att(char* sxT, float* lbuf,
        const half8 (&af0)[2],
        const float* __restrict__ attw, const float* __restrict__ attb,
        int col, int g, int lane) {
    half8 hq[NP];                      // packed h: {ch 4g..4g+3, 16+4g..19+4g}
    #pragma unroll
    for (int i = 0; i < NP; ++i) {
        const int p = P0 + i;
        half8 bf = *(const half8*)(sxT + col * Y_BS + p * Y_RS + g * 16);
        const f32x4 z = {0.f, 0.f, 0.f, 0.f};
        f32x4 h0 = __builtin_amdgcn_mfma_f32_16x16x32_f16(af0[0], bf, z, 0, 0, 0);
        f32x4 h1 = __builtin_amdgcn_mfma_f32_16x16x32_f16(af0[1], bf, z, 0, 0, 0);
        float4 a0 = *(const float4*)(attw + p * 32 + 4 * g);
        float4 a1 = *(const float4*)(attw + p * 32 + 16 + 4 * g);
        float lp = h0[0] * a0.x;
        lp = fmaf(h0[1], a0.y, lp); lp = fmaf(h0[2], a0.z, lp);
        lp = fmaf(h0[3], a0.w, lp); lp = fmaf(h1[0], a1.x, lp);
        lp = fmaf(h1[1], a1.y, lp); lp = fmaf(h1[2], a1.z, lp);
        lp = fmaf(h1[3], a1.w, lp);
        lp += __shfl_xor(lp, 16, 64);
        lp += __shfl_xor(lp, 32, 64);
        if (lane < 16) lbuf[lane * 20 + p] = lp + attb[p];
        uint4 u;
        u.x = pack2h(h0[0], h0[1]); u.y = pack2h(h0[2], h0[3]);
        u.z = pack2h(h1[0], h1[1]); u.w = pack2h(h1[2], h1[3]);
        hq[i] = __builtin_bit_cast(half8, u);
    }
    __syncthreads();    // all 15 logits visible; all conv0 x-reads complete
    const float* lb = lbuf + col * 20;
    float4 l0 = *(const float4*)(lb + 0);
    float4 l1 = *(const float4*)(lb + 4);
    float4 l2 = *(const float4*)(lb + 8);
    float4 l3 = *(const float4*)(lb + 12);      // .w garbage, unused
    float lg[15] = {l0.x,l0.y,l0.z,l0.w, l1.x,l1.y,l1.z,l1.w,
                    l2.x,l2.y,l2.z,l2.w, l3.x,l3.y,l3.z};
    float mA = fmaxf(fmaxf(fmaxf(lg[0],lg[1]), fmaxf(lg[2],lg[3])),
                     fmaxf(fmaxf(lg[4],lg[5]), fmaxf(lg[6],lg[7])));
    float mB = fmaxf(fmaxf(fmaxf(lg[8],lg[9]), fmaxf(lg[10],lg[11])),
                     fmaxf(fmaxf(lg[12],lg[13]), lg[14]));
    const float mx = fmaxf(mA, mB);
    float e[15];
    #pragma unroll
    for (int l = 0; l < 15; ++l) e[l] = __expf(lg[l] - mx);
    float sA = ((e[0]+e[1]) + (e[2]+e[3])) + ((e[4]+e[5]) + (e[6]+e[7]));
    float sB = ((e[8]+e[9]) + (e[10]+e[11])) + ((e[12]+e[13]) + e[14]);
    const float inv = 1.f / (sA + sB);
    #pragma unroll
    for (int i = 0; i < NP; ++i) {
        const int p = P0 + i;
        half8 ys = hq[i] * splat8(e[p] * inv);   // v_pk_mul_f16
        uint4 u = __builtin_bit_cast(uint4, ys);
        char* yr = sxT + col * Y_BS + p * Y_RS;
        uint2 u0; u0.x = u.x; u0.y = u.y;
        uint2 u1; u1.x = u.z; u1.y = u.w;
        *(uint2*)(yr + 8 * g) = u0;              // channels 4g..4g+3
        *(uint2*)(yr + 32 + 8 * g) = u1;         // channels 16+4g..19+4g
    }
}

// ---- conv1 half-sweep H from prefolded fragments -> frH register B-fragments ----
template<int H, int R0, int NR>
__device__ __forceinline__ void conv1_half(
    const char* __restrict__ yb, half8 (&frH)[NR],
    const int lane, const int g, const char* __restrict__ ws)
{
    const uint4* wf1 = (const uint4*)(ws + WF1_OFF);
    half8 afA[3], afB[3];
    #pragma unroll
    for (int s = 0; s < 3; ++s) {
        afA[s] = __builtin_bit_cast(half8, wf1[((H*2 + 0)*3 + s)*64 + lane]);
        afB[s] = __builtin_bit_cast(half8, wf1[((H*2 + 1)*3 + s)*64 + lane]);
    }
    const float* sh1 = (const float*)(ws + SH1_OFF) + g*16 + H*8;
    float4 shv0 = *(const float4*)(sh1);
    float4 shv1 = *(const float4*)(sh1 + 4);
    const float sh[8] = {shv0.x, shv0.y, shv0.z, shv0.w, shv1.x, shv1.y, shv1.z, shv1.w};

    half8 y3[3];
    y3[(R0 + 0) % 3] = *(const half8*)(yb + (R0 + 0) * Y_RS + g * 16);
    y3[(R0 + 1) % 3] = *(const half8*)(yb + (R0 + 1) * Y_RS + g * 16);
    #pragma unroll
    for (int i = 0; i < NR; ++i) {
        const int r = R0 + i;
        y3[(r + 2) % 3] = *(const half8*)(yb + (r + 2) * Y_RS + g * 16);
        f32x4 a0 = {0.f,0.f,0.f,0.f}, a1 = {0.f,0.f,0.f,0.f};
        #pragma unroll
        for (int s = 0; s < 3; ++s) {
            const half8 yy = y3[(r + s) % 3];
            a0 = __builtin_amdgcn_mfma_f32_16x16x32_f16(afA[s], yy, a0, 0,0,0);
            a1 = __builtin_amdgcn_mfma_f32_16x16x32_f16(afB[s], yy, a1, 0,0,0);
        }
        float z0[4], z1[4];
        #pragma unroll
        for (int r2 = 0; r2 < 4; ++r2) {
            float t0 = a0[r2] + sh[r2];     z0[r2] = fmaxf(t0, 0.01f*t0);
            float t1 = a1[r2] + sh[4+r2];   z1[r2] = fmaxf(t1, 0.01f*t1);
        }
        uint4 u;
        u.x = pack2h(z0[0], z0[1]); u.y = pack2h(z0[2], z0[3]);
        u.z = pack2h(z1[0], z1[1]); u.w = pack2h(z1[2], z1[3]);
        frH[i] = __builtin_bit_cast(half8, u);
    }
}

// ---- conv2 tile MT from prefolded fragments -> LDS out staging ----
template<int MT, int P0, int NP, int NR>
__device__ __forceinline__ void conv2_tile(
    float* __restrict__ sout, const half8 (&fr0)[NR], const half8 (&fr1)[NR],
    const int col, const int g, const int lane, const char* __restrict__ ws)
{
    const uint4* wf2 = (const uint4*)(ws + WF2_OFF);
    half8 af3[6];
    #pragma unroll
    for (int hh = 0; hh < 2; ++hh)
    #pragma unroll
    for (int tap = 0; tap < 3; ++tap)
        af3[tap*2 + hh] = __builtin_bit_cast(half8, wf2[((MT*2 + hh)*3 + tap)*64 + lane]);
    float4 shv = *(const float4*)((const float*)(ws + SH2_OFF) + g*8 + MT*4);
    const float sh2[4] = {shv.x, shv.y, shv.z, shv.w};

    #pragma unroll
    for (int pp = 0; pp < NP; ++pp) {
        const int p = P0 + pp;
        f32x4 acc = {0.f,0.f,0.f,0.f};
        #pragma unroll
        for (int s = 0; s < 6; ++s) {
            const half8 bb = (s & 1) ? fr1[pp + (s >> 1)] : fr0[pp + (s >> 1)];
            acc = __builtin_amdgcn_mfma_f32_16x16x32_f16(af3[s], bb, acc, 0,0,0);
        }
        #pragma unroll
        for (int r = 0; r < 4; ++r) {
            const int oc = MT*16 + 4*g + r;
            if (oc < 20) {
                float t0 = acc[r] + sh2[r];
                t0 = fmaxf(t0, 0.01f*t0);
                sout[col*OUT_SDW + oc*11 + p] = t0;
            }
        }
    }
}

// ---- conv1 (two half-sweeps) -> fr regs -> conv2 (two tile-sweeps) -> LDS staging ----
template<int R0, int NR, int P0, int NP>
__device__ __forceinline__ void stack23(
    char* __restrict__ sxT, const int col, const int g, const int lane,
    const char* __restrict__ ws)
{
    float* sout = (float*)sxT;
    const char* yb = sxT + col * Y_BS;
    half8 fr0[NR], fr1[NR];
    conv1_half<0, R0, NR>(yb, fr0, lane, g, ws);
    __builtin_amdgcn_sched_barrier(0);    // keep the two halves' af live-ranges separate
    conv1_half<1, R0, NR>(yb, fr1, lane, g, ws);
    __syncthreads();   // all y reads done before out staging overwrites sxT
    conv2_tile<0, P0, NP, NR>(sout, fr0, fr1, col, g, lane, ws);
    __builtin_amdgcn_sched_barrier(0);
    conv2_tile<1, P0, NP, NR>(sout, fr0, fr1, col, g, lane, ws);
}

__global__ __launch_bounds__(THREADS, 2)
void peptide_v17(const float* __restrict__ x,
                 const float* __restrict__ attw,   // [15][32]
                 const float* __restrict__ attb,   // [15]
                 const char*  __restrict__ ws,     // prefolded fragments
                 float* __restrict__ out)          // [B][20][11]
{
    __shared__ __align__(16) char smem[SMEM_BYTES];
    char* sxT = smem;
    float* lbuf = (float*)(smem + LB_OFF);

    const int tid  = threadIdx.x;
    const int lane = tid & 63;
    const int wv   = tid >> 6;
    const int col  = lane & 15;
    const int g    = lane >> 4;

    // ---- quad-gather transpose: 192 tasks = (ch-group 0..2)*(p-quad 0..3)*(batch 0..15)
    //      ordered so ch is wave-uniform; each task: <=8 dwordx4 loads spanning 4 positions
    {
        const float* xg = x + (size_t)blockIdx.x * (BPB * 315);
        #pragma unroll
        for (int q = 0; q < 2; ++q) {
            const int u = q * THREADS + tid;
            if (u < 192) {
                const int b2 = u & 15;
                const int qd = (u >> 4) & 3;
                const int ch = u >> 6;               // 0,1,2 (wave-uniform)
                const int po = (qd == 3) ? 11 : 4 * qd;
                const float* src = xg + b2 * 315 + po;
                char* dstb = sxT + b2 * Y_BS + ch * 16;
                if (ch < 2) {
                    f32x4 v4[8];
                    #pragma unroll
                    for (int j = 0; j < 8; ++j)
                        v4[j] = *(const f32x4*)(src + (ch * 8 + j) * 15);
                    #pragma unroll
                    for (int e = 0; e < 4; ++e) {
                        if (qd < 3 || e > 0) {
                            const int p = po + e;
                            uint4 d;
                            d.x = pkrtz(v4[0][e], v4[1][e]);
                            d.y = pkrtz(v4[2][e], v4[3][e]);
                            d.z = pkrtz(v4[4][e], v4[5][e]);
                            d.w = pkrtz(v4[6][e], v4[7][e]);
                            *(uint4*)(dstb + p * Y_RS) = d;
                        }
                    }
                } else {
                    f32x4 v4[5];
                    #pragma unroll
                    for (int j = 0; j < 5; ++j)
                        v4[j] = *(const f32x4*)(src + (16 + j) * 15);
                    const uint4 zz = {0u, 0u, 0u, 0u};
                    #pragma unroll
                    for (int e = 0; e < 4; ++e) {
                        if (qd < 3 || e > 0) {
                            const int p = po + e;
                            uint4 d;
                            d.x = pkrtz(v4[0][e], v4[1][e]);
                            d.y = pkrtz(v4[2][e], v4[3][e]);
                            d.z = pkrtz(v4[4][e], 0.f);
                            d.w = 0u;
                            *(uint4*)(dstb + p * Y_RS) = d;        // ch 16..23
                            *(uint4*)(dstb + p * Y_RS + 16) = zz;  // ch 24..31
                        }
                    }
                }
            }
        }
    }

    // conv0 A-fragments from d_ws
    half8 af0[2];
    {
        const uint4* wf0 = (const uint4*)ws;
        af0[0] = __builtin_bit_cast(half8, wf0[lane]);
        af0[1] = __builtin_bit_cast(half8, wf0[64 + lane]);
    }
    __syncthreads();                      // xT ready

    // ---- conv0 MFMA + attention softmax (y in-place) ----
    if (wv == 0) conv0_att<0, 8>(sxT, lbuf, af0, attw, attb, col, g, lane);
    else         conv0_att<8, 7>(sxT, lbuf, af0, attw, attb, col, g, lane);
    __syncthreads();                      // y complete (cross-wave rows)

    // ---- conv1 -> regs -> conv2 -> out staging ----
    if (wv == 0) stack23<0, 8, 0, 6>(sxT, col, g, lane, ws);
    else         stack23<6, 7, 6, 5>(sxT, col, g, lane, ws);
    __syncthreads();                      // out staging complete

    // ---- gap-free coalesced copy-out: 16 x 220 dw = one 14080 B span ----
    {
        float* ob = out + (size_t)blockIdx.x * (BPB * 220);
        const float* sf = (const float*)sxT;
        #pragma unroll
        for (int j = 0; j < 7; ++j) {
            const int u = j * THREADS + tid;          // 16B unit
            if (u < 880) {
                f32x4 v = *(const f32x4*)(sf + u * 4);
                *(f32x4*)(ob + u * 4) = v;
            }
        }
    }
}

extern "C" void kernel_launch(void* const* d_in, const int* in_sizes, int n_in,
                              void* d_out, int out_size, void* d_ws, size_t ws_size,
                              hipStream_t stream) {
    const float* x    = (const float*)d_in[0];
    const float* w0   = (const float*)d_in[1];
    const float* attw = (const float*)d_in[2];
    const float* attb = (const float*)d_in[3];
    const float* w1   = (const float*)d_in[4];
    const float* cb1  = (const float*)d_in[5];
    const float* g1   = (const float*)d_in[6];
    const float* bt1  = (const float*)d_in[7];
    const float* mn1  = (const float*)d_in[8];
    const float* vr1  = (const float*)d_in[9];
    const float* w2   = (const float*)d_in[10];
    const float* cb2  = (const float*)d_in[11];
    const float* g2   = (const float*)d_in[12];
    const float* bt2  = (const float*)d_in[13];
    const float* mn2  = (const float*)d_in[14];
    const float* vr2  = (const float*)d_in[15];

    hipLaunchKernelGGL(peptide_prep, dim3(1), dim3(64), 0, stream,
                       w0, w1, cb1, g1, bt1, mn1, vr1,
                       w2, cb2, g2, bt2, mn2, vr2, (char*)d_ws);
    hipLaunchKernelGGL(peptide_v17, dim3(NBLOCKS), dim3(THREADS), 0, stream,
                       x, attw, attb, (const char*)d_ws, (float*)d_out);
}

// Round 18
// 88.466 us; speedup vs baseline: 1.2100x; 1.0896x over previous
//
#include <hip/hip_runtime.h>

#define NBATCH  131072
#define THREADS 128
#define BPB     16
#define NBLOCKS (NBATCH / BPB)     // 8192

typedef __attribute__((ext_vector_type(8))) _Float16 half8;
typedef __attribute__((ext_vector_type(4))) float f32x4;

// LDS (bytes): sxT f16 [16 b][15 p][80B: 64B = ch 0..31 (21 data + 11 zero), 16B pad]
//              conv0 writes y in place; stage3 reuses [0,14080) as out f32 [16][220]
//  [19200, 20480):  lbuf f32 [16][20]  logit exchange
#define Y_RS 80
#define Y_BS 1200
#define LB_OFF 19200
#define SMEM_BYTES 20480
#define OUT_SDW 220

// d_ws layout (bytes):
#define WF1_OFF 2048
#define WF2_OFF 14336
#define SH1_OFF 26624
#define SH2_OFF 26880

static __device__ __forceinline__ unsigned short f2h(float f) {
    return __builtin_bit_cast(unsigned short, (_Float16)f);   // RNE
}
static __device__ __forceinline__ unsigned int pack2h(float a, float b) {
    return (unsigned int)f2h(a) | ((unsigned int)f2h(b) << 16);
}
static __device__ __forceinline__ unsigned int pkrtz(float a, float b) {
    __fp16 __attribute__((ext_vector_type(2))) h =
        __builtin_amdgcn_cvt_pkrtz(a, b);                     // 1 VALU op, RTZ
    return __builtin_bit_cast(unsigned int, h);
}
static __device__ __forceinline__ half8 splat8(float s) {
    const _Float16 h = (_Float16)s;
    half8 v;
    #pragma unroll
    for (int j = 0; j < 8; ++j) v[j] = h;
    return v;
}

// ============ prep kernel (4 waves, work split): fold BN, pack fragments ============
__global__ __launch_bounds__(256, 1)
void peptide_prep(const float* __restrict__ w0,
                  const float* __restrict__ w1, const float* __restrict__ cb1,
                  const float* __restrict__ g1, const float* __restrict__ bt1,
                  const float* __restrict__ mn1, const float* __restrict__ vr1,
                  const float* __restrict__ w2, const float* __restrict__ cb2,
                  const float* __restrict__ g2, const float* __restrict__ bt2,
                  const float* __restrict__ mn2, const float* __restrict__ vr2,
                  char* __restrict__ ws)
{
    const int tid  = threadIdx.x;
    const int lane = tid & 63;
    const int wv   = tid >> 6;
    const int col = lane & 15, g = lane >> 4;
    uint4* wf0 = (uint4*)ws;
    uint4* wf1 = (uint4*)(ws + WF1_OFF);
    uint4* wf2 = (uint4*)(ws + WF2_OFF);
    float* sh1 = (float*)(ws + SH1_OFF);
    float* sh2 = (float*)(ws + SH2_OFF);

    if (wv == 0) {
        // conv0 fragments
        #pragma unroll
        for (int mt = 0; mt < 2; ++mt) {
            const int o = mt * 16 + col;
            half8 fh;
            #pragma unroll
            for (int j = 0; j < 8; ++j) {
                const int c = 8 * g + j;
                fh[j] = (c < 21) ? (_Float16)w0[o * 21 + c] : (_Float16)0.f;
            }
            wf0[mt * 64 + lane] = __builtin_bit_cast(uint4, fh);
        }
        // shift vectors (per g)
        if (col == 0) {
            #pragma unroll
            for (int k = 0; k < 16; ++k) {
                const int H = k >> 3, t = (k >> 2) & 1, r = k & 3;
                const int o = 32*H + 8*g + 4*t + r;
                const float iva = g1[o] * rsqrtf(vr1[o] + 1e-5f);
                sh1[g*16 + k] = bt1[o] + (cb1[o] - mn1[o]) * iva;
            }
            #pragma unroll
            for (int k = 0; k < 8; ++k) {
                const int MT = k >> 2, r = k & 3;
                const int oc = MT*16 + 4*g + r;
                if (oc < 20) {
                    const float iva = g2[oc] * rsqrtf(vr2[oc] + 1e-5f);
                    sh2[g*8 + k] = bt2[oc] + (cb2[oc] - mn2[oc]) * iva;
                } else sh2[g*8 + k] = 0.f;
            }
        }
    } else if (wv < 3) {
        // conv1 fragments, half H = wv-1; chan1 = 32H + 8(col>>2) + 4t + (col&3)
        const int H = wv - 1;
        #pragma unroll
        for (int t = 0; t < 2; ++t) {
            const int o = 32*H + 8*(col>>2) + 4*t + (col&3);
            const float iva = g1[o] * rsqrtf(vr1[o] + 1e-5f);
            #pragma unroll
            for (int s = 0; s < 3; ++s) {
                half8 fh;
                #pragma unroll
                for (int j = 0; j < 8; ++j)
                    fh[j] = (_Float16)(w1[o*96 + g*24 + j*3 + s] * iva);
                wf1[((H*2 + t)*3 + s)*64 + lane] = __builtin_bit_cast(uint4, fh);
            }
        }
    } else {
        // conv2 fragments, bn2 folded, zero for o >= 20
        #pragma unroll
        for (int MT = 0; MT < 2; ++MT) {
            const int o = MT * 16 + col;
            const float iva = (o < 20) ? g2[o] * rsqrtf(vr2[o] + 1e-5f) : 0.f;
            #pragma unroll
            for (int hh = 0; hh < 2; ++hh)
            #pragma unroll
            for (int tap = 0; tap < 3; ++tap) {
                half8 fh;
                #pragma unroll
                for (int j = 0; j < 8; ++j)
                    fh[j] = (o < 20) ? (_Float16)(w2[o*192 + hh*96 + g*24 + j*3 + tap] * iva)
                                     : (_Float16)0.f;
                wf2[((MT*2 + hh)*3 + tap)*64 + lane] = __builtin_bit_cast(uint4, fh);
            }
        }
    }
}

// ---- conv0 via MFMA + attention softmax; h packed f16; y in-place to sxT ----
template<int P0, int NP>
__device__ __forceinline__ void conv0_att(char* sxT, float* lbuf,
        const half8 (&af0)[2],
        const float* __restrict__ attw, const float* __restrict__ attb,
        int col, int g, int lane) {
    half8 hq[NP];                      // packed h: {ch 4g..4g+3, 16+4g..19+4g}
    #pragma unroll
    for (int i = 0; i < NP; ++i) {
        const int p = P0 + i;
        half8 bf = *(const half8*)(sxT + col * Y_BS + p * Y_RS + g * 16);
        const f32x4 z = {0.f, 0.f, 0.f, 0.f};
        f32x4 h0 = __builtin_amdgcn_mfma_f32_16x16x32_f16(af0[0], bf, z, 0, 0, 0);
        f32x4 h1 = __builtin_amdgcn_mfma_f32_16x16x32_f16(af0[1], bf, z, 0, 0, 0);
        float4 a0 = *(const float4*)(attw + p * 32 + 4 * g);
        float4 a1 = *(const float4*)(attw + p * 32 + 16 + 4 * g);
        float lp = h0[0] * a0.x;
        lp = fmaf(h0[1], a0.y, lp); lp = fmaf(h0[2], a0.z, lp);
        lp = fmaf(h0[3], a0.w, lp); lp = fmaf(h1[0], a1.x, lp);
        lp = fmaf(h1[1], a1.y, lp); lp = fmaf(h1[2], a1.z, lp);
        lp = fmaf(h1[3], a1.w, lp);
        lp += __shfl_xor(lp, 16, 64);
        lp += __shfl_xor(lp, 32, 64);
        if (lane < 16) lbuf[lane * 20 + p] = lp + attb[p];
        uint4 u;
        u.x = pkrtz(h0[0], h0[1]); u.y = pkrtz(h0[2], h0[3]);
        u.z = pkrtz(h1[0], h1[1]); u.w = pkrtz(h1[2], h1[3]);
        hq[i] = __builtin_bit_cast(half8, u);
    }
    __syncthreads();    // all 15 logits visible; all conv0 x-reads complete
    const float* lb = lbuf + col * 20;
    float4 l0 = *(const float4*)(lb + 0);
    float4 l1 = *(const float4*)(lb + 4);
    float4 l2 = *(const float4*)(lb + 8);
    float4 l3 = *(const float4*)(lb + 12);      // .w garbage, unused
    float lg[15] = {l0.x,l0.y,l0.z,l0.w, l1.x,l1.y,l1.z,l1.w,
                    l2.x,l2.y,l2.z,l2.w, l3.x,l3.y,l3.z};
    float mA = fmaxf(fmaxf(fmaxf(lg[0],lg[1]), fmaxf(lg[2],lg[3])),
                     fmaxf(fmaxf(lg[4],lg[5]), fmaxf(lg[6],lg[7])));
    float mB = fmaxf(fmaxf(fmaxf(lg[8],lg[9]), fmaxf(lg[10],lg[11])),
                     fmaxf(fmaxf(lg[12],lg[13]), lg[14]));
    const float mx = fmaxf(mA, mB);
    float e[15];
    #pragma unroll
    for (int l = 0; l < 15; ++l) e[l] = __expf(lg[l] - mx);
    float sA = ((e[0]+e[1]) + (e[2]+e[3])) + ((e[4]+e[5]) + (e[6]+e[7]));
    float sB = ((e[8]+e[9]) + (e[10]+e[11])) + ((e[12]+e[13]) + e[14]);
    const float inv = 1.f / (sA + sB);
    #pragma unroll
    for (int i = 0; i < NP; ++i) {
        const int p = P0 + i;
        half8 ys = hq[i] * splat8(e[p] * inv);   // v_pk_mul_f16
        uint4 u = __builtin_bit_cast(uint4, ys);
        char* yr = sxT + col * Y_BS + p * Y_RS;
        uint2 u0; u0.x = u.x; u0.y = u.y;
        uint2 u1; u1.x = u.z; u1.y = u.w;
        *(uint2*)(yr + 8 * g) = u0;              // channels 4g..4g+3
        *(uint2*)(yr + 32 + 8 * g) = u1;         // channels 16+4g..19+4g
    }
}

// ---- conv1 half-sweep H from prefolded fragments -> frH register B-fragments ----
template<int H, int R0, int NR>
__device__ __forceinline__ void conv1_half(
    const char* __restrict__ yb, half8 (&frH)[NR],
    const int lane, const int g, const char* __restrict__ ws)
{
    const uint4* wf1 = (const uint4*)(ws + WF1_OFF);
    half8 afA[3], afB[3];
    #pragma unroll
    for (int s = 0; s < 3; ++s) {
        afA[s] = __builtin_bit_cast(half8, wf1[((H*2 + 0)*3 + s)*64 + lane]);
        afB[s] = __builtin_bit_cast(half8, wf1[((H*2 + 1)*3 + s)*64 + lane]);
    }
    const float* sh1 = (const float*)(ws + SH1_OFF) + g*16 + H*8;
    float4 shv0 = *(const float4*)(sh1);
    float4 shv1 = *(const float4*)(sh1 + 4);

    half8 y3[3];
    y3[(R0 + 0) % 3] = *(const half8*)(yb + (R0 + 0) * Y_RS + g * 16);
    y3[(R0 + 1) % 3] = *(const half8*)(yb + (R0 + 1) * Y_RS + g * 16);
    #pragma unroll
    for (int i = 0; i < NR; ++i) {
        const int r = R0 + i;
        y3[(r + 2) % 3] = *(const half8*)(yb + (r + 2) * Y_RS + g * 16);
        // acc-init = bn1 shifts (saves the epilogue adds; numerics identical)
        f32x4 a0 = {shv0.x, shv0.y, shv0.z, shv0.w};
        f32x4 a1 = {shv1.x, shv1.y, shv1.z, shv1.w};
        #pragma unroll
        for (int s = 0; s < 3; ++s) {
            const half8 yy = y3[(r + s) % 3];
            a0 = __builtin_amdgcn_mfma_f32_16x16x32_f16(afA[s], yy, a0, 0,0,0);
            a1 = __builtin_amdgcn_mfma_f32_16x16x32_f16(afB[s], yy, a1, 0,0,0);
        }
        float z0[4], z1[4];
        #pragma unroll
        for (int r2 = 0; r2 < 4; ++r2) {
            z0[r2] = fmaxf(a0[r2], 0.01f * a0[r2]);
            z1[r2] = fmaxf(a1[r2], 0.01f * a1[r2]);
        }
        uint4 u;
        u.x = pkrtz(z0[0], z0[1]); u.y = pkrtz(z0[2], z0[3]);
        u.z = pkrtz(z1[0], z1[1]); u.w = pkrtz(z1[2], z1[3]);
        frH[i] = __builtin_bit_cast(half8, u);
    }
}

// ---- conv2 tile MT from prefolded fragments -> LDS out staging ----
template<int MT, int P0, int NP, int NR>
__device__ __forceinline__ void conv2_tile(
    float* __restrict__ sout, const half8 (&fr0)[NR], const half8 (&fr1)[NR],
    const int col, const int g, const int lane, const char* __restrict__ ws)
{
    const uint4* wf2 = (const uint4*)(ws + WF2_OFF);
    half8 af3[6];
    #pragma unroll
    for (int hh = 0; hh < 2; ++hh)
    #pragma unroll
    for (int tap = 0; tap < 3; ++tap)
        af3[tap*2 + hh] = __builtin_bit_cast(half8, wf2[((MT*2 + hh)*3 + tap)*64 + lane]);
    float4 shv = *(const float4*)((const float*)(ws + SH2_OFF) + g*8 + MT*4);

    #pragma unroll
    for (int pp = 0; pp < NP; ++pp) {
        const int p = P0 + pp;
        f32x4 acc = {shv.x, shv.y, shv.z, shv.w};   // acc-init = bn2 shifts
        #pragma unroll
        for (int s = 0; s < 6; ++s) {
            const half8 bb = (s & 1) ? fr1[pp + (s >> 1)] : fr0[pp + (s >> 1)];
            acc = __builtin_amdgcn_mfma_f32_16x16x32_f16(af3[s], bb, acc, 0,0,0);
        }
        #pragma unroll
        for (int r = 0; r < 4; ++r) {
            const int oc = MT*16 + 4*g + r;
            if (oc < 20) {
                float t0 = fmaxf(acc[r], 0.01f * acc[r]);
                sout[col*OUT_SDW + oc*11 + p] = t0;
            }
        }
    }
}

// ---- conv1 (two half-sweeps) -> fr regs -> conv2 (two tile-sweeps) -> LDS staging ----
template<int R0, int NR, int P0, int NP>
__device__ __forceinline__ void stack23(
    char* __restrict__ sxT, const int col, const int g, const int lane,
    const char* __restrict__ ws)
{
    float* sout = (float*)sxT;
    const char* yb = sxT + col * Y_BS;
    half8 fr0[NR], fr1[NR];
    conv1_half<0, R0, NR>(yb, fr0, lane, g, ws);
    __builtin_amdgcn_sched_barrier(0);    // keep the two halves' af live-ranges separate
    conv1_half<1, R0, NR>(yb, fr1, lane, g, ws);
    __syncthreads();   // all y reads done before out staging overwrites sxT
    conv2_tile<0, P0, NP, NR>(sout, fr0, fr1, col, g, lane, ws);
    __builtin_amdgcn_sched_barrier(0);
    conv2_tile<1, P0, NP, NR>(sout, fr0, fr1, col, g, lane, ws);
}

__global__ __launch_bounds__(THREADS, 2)
void peptide_v18(const float* __restrict__ x,
                 const float* __restrict__ attw,   // [15][32]
                 const float* __restrict__ attb,   // [15]
                 const char*  __restrict__ ws,     // prefolded fragments
                 float* __restrict__ out)          // [B][20][11]
{
    __shared__ __align__(16) char smem[SMEM_BYTES];
    char* sxT = smem;
    float* lbuf = (float*)(smem + LB_OFF);

    const int tid  = threadIdx.x;
    const int lane = tid & 63;
    const int wv   = tid >> 6;
    const int col  = lane & 15;
    const int g    = lane >> 4;

    // ---- quad-gather transpose: 192 tasks = (ch-group 0..2)*(p-quad 0..3)*(batch 0..15)
    {
        const float* xg = x + (size_t)blockIdx.x * (BPB * 315);
        #pragma unroll
        for (int q = 0; q < 2; ++q) {
            const int u = q * THREADS + tid;
            if (u < 192) {
                const int b2 = u & 15;
                const int qd = (u >> 4) & 3;
                const int ch = u >> 6;               // 0,1,2 (wave-uniform)
                const int po = (qd == 3) ? 11 : 4 * qd;
                const float* src = xg + b2 * 315 + po;
                char* dstb = sxT + b2 * Y_BS + ch * 16;
                if (ch < 2) {
                    f32x4 v4[8];
                    #pragma unroll
                    for (int j = 0; j < 8; ++j)
                        v4[j] = *(const f32x4*)(src + (ch * 8 + j) * 15);
                    #pragma unroll
                    for (int e = 0; e < 4; ++e) {
                        if (qd < 3 || e > 0) {
                            const int p = po + e;
                            uint4 d;
                            d.x = pkrtz(v4[0][e], v4[1][e]);
                            d.y = pkrtz(v4[2][e], v4[3][e]);
                            d.z = pkrtz(v4[4][e], v4[5][e]);
                            d.w = pkrtz(v4[6][e], v4[7][e]);
                            *(uint4*)(dstb + p * Y_RS) = d;
                        }
                    }
                } else {
                    f32x4 v4[5];
                    #pragma unroll
                    for (int j = 0; j < 5; ++j)
                        v4[j] = *(const f32x4*)(src + (16 + j) * 15);
                    const uint4 zz = {0u, 0u, 0u, 0u};
                    #pragma unroll
                    for (int e = 0; e < 4; ++e) {
                        if (qd < 3 || e > 0) {
                            const int p = po + e;
                            uint4 d;
                            d.x = pkrtz(v4[0][e], v4[1][e]);
                            d.y = pkrtz(v4[2][e], v4[3][e]);
                            d.z = pkrtz(v4[4][e], 0.f);
                            d.w = 0u;
                            *(uint4*)(dstb + p * Y_RS) = d;        // ch 16..23
                            *(uint4*)(dstb + p * Y_RS + 16) = zz;  // ch 24..31
                        }
                    }
                }
            }
        }
    }

    // conv0 A-fragments from d_ws
    half8 af0[2];
    {
        const uint4* wf0 = (const uint4*)ws;
        af0[0] = __builtin_bit_cast(half8, wf0[lane]);
        af0[1] = __builtin_bit_cast(half8, wf0[64 + lane]);
    }
    __syncthreads();                      // xT ready

    // ---- conv0 MFMA + attention softmax (y in-place) ----
    if (wv == 0) conv0_att<0, 8>(sxT, lbuf, af0, attw, attb, col, g, lane);
    else         conv0_att<8, 7>(sxT, lbuf, af0, attw, attb, col, g, lane);
    __syncthreads();                      // y complete (cross-wave rows)

    // ---- conv1 -> regs -> conv2 -> out staging ----
    if (wv == 0) stack23<0, 8, 0, 6>(sxT, col, g, lane, ws);
    else         stack23<6, 7, 6, 5>(sxT, col, g, lane, ws);
    __syncthreads();                      // out staging complete

    // ---- gap-free coalesced copy-out: 16 x 220 dw = one 14080 B span ----
    {
        float* ob = out + (size_t)blockIdx.x * (BPB * 220);
        const float* sf = (const float*)sxT;
        #pragma unroll
        for (int j = 0; j < 7; ++j) {
            const int u = j * THREADS + tid;          // 16B unit
            if (u < 880) {
                f32x4 v = *(const f32x4*)(sf + u * 4);
                *(f32x4*)(ob + u * 4) = v;
            }
        }
    }
}

extern "C" void kernel_launch(void* const* d_in, const int* in_sizes, int n_in,
                              void* d_out, int out_size, void* d_ws, size_t ws_size,
                              hipStream_t stream) {
    const float* x    = (const float*)d_in[0];
    const float* w0   = (const float*)d_in[1];
    const float* attw = (const float*)d_in[2];
    const float* attb = (const float*)d_in[3];
    const float* w1   = (const float*)d_in[4];
    const float* cb1  = (const float*)d_in[5];
    const float* g1   = (const float*)d_in[6];
    const float* bt1  = (const float*)d_in[7];
    const float* mn1  = (const float*)d_in[8];
    const float* vr1  = (const float*)d_in[9];
    const float* w2   = (const float*)d_in[10];
    const float* cb2  = (const float*)d_in[11];
    const float* g2   = (const float*)d_in[12];
    const float* bt2  = (const float*)d_in[13];
    const float* mn2  = (const float*)d_in[14];
    const float* vr2  = (const float*)d_in[15];

    hipLaunchKernelGGL(peptide_prep, dim3(1), dim3(256), 0, stream,
                       w0, w1, cb1, g1, bt1, mn1, vr1,
                       w2, cb2, g2, bt2, mn2, vr2, (char*)d_ws);
    hipLaunchKernelGGL(peptide_v18, dim3(NBLOCKS), dim3(THREADS), 0, stream,
                       x, attw, attb, (const char*)d_ws, (float*)d_out);
}

// Round 19
// 81.235 us; speedup vs baseline: 1.3177x; 1.0890x over previous
//
#include <hip/hip_runtime.h>

#define NBATCH  131072
#define THREADS 128
#define BPB     16
#define NBLOCKS (NBATCH / BPB)     // 8192

typedef __attribute__((ext_vector_type(8))) _Float16 half8;
typedef __attribute__((ext_vector_type(4))) float f32x4;

// LDS (bytes): sxT f16 [16 b][15 p][80B: 64B = ch 0..31 (21 data + 11 zero), 16B pad]
//              conv0 writes y in place; stage3 reuses [0,14080) as out f32 [16][220]
//  [19200, 20480):  lbuf f32 [16][20]  logit exchange
#define Y_RS 80
#define Y_BS 1200
#define LB_OFF 19200
#define SMEM_BYTES 20480
#define OUT_SDW 220

// d_ws layout (bytes):
#define WF1_OFF 2048
#define WF2_OFF 14336
#define SH1_OFF 26624
#define SH2_OFF 26880
#define WFA_OFF 27008      // att logit A-fragment: uint4[64]
#define ATTB_OFF 28032     // padded attb: f32[16]

static __device__ __forceinline__ unsigned int pkrtz(float a, float b) {
    __fp16 __attribute__((ext_vector_type(2))) h =
        __builtin_amdgcn_cvt_pkrtz(a, b);                     // 1 VALU op, RTZ
    return __builtin_bit_cast(unsigned int, h);
}
static __device__ __forceinline__ half8 splat8(float s) {
    const _Float16 h = (_Float16)s;
    half8 v;
    #pragma unroll
    for (int j = 0; j < 8; ++j) v[j] = h;
    return v;
}

// ============ prep kernel (4 waves, work split): fold BN, pack fragments ============
__global__ __launch_bounds__(256, 1)
void peptide_prep(const float* __restrict__ w0,
                  const float* __restrict__ attw, const float* __restrict__ attb,
                  const float* __restrict__ w1, const float* __restrict__ cb1,
                  const float* __restrict__ g1, const float* __restrict__ bt1,
                  const float* __restrict__ mn1, const float* __restrict__ vr1,
                  const float* __restrict__ w2, const float* __restrict__ cb2,
                  const float* __restrict__ g2, const float* __restrict__ bt2,
                  const float* __restrict__ mn2, const float* __restrict__ vr2,
                  char* __restrict__ ws)
{
    const int tid  = threadIdx.x;
    const int lane = tid & 63;
    const int wv   = tid >> 6;
    const int col = lane & 15, g = lane >> 4;
    uint4* wf0 = (uint4*)ws;
    uint4* wf1 = (uint4*)(ws + WF1_OFF);
    uint4* wf2 = (uint4*)(ws + WF2_OFF);
    float* sh1 = (float*)(ws + SH1_OFF);
    float* sh2 = (float*)(ws + SH2_OFF);

    if (wv == 0) {
        // conv0 fragments, chan0(mt,row) = 8*(row>>2) + 4*mt + (row&3):
        // lane (col,g) accumulates channels 8g..8g+7 across both tiles
        #pragma unroll
        for (int mt = 0; mt < 2; ++mt) {
            const int oc = 8*(col>>2) + 4*mt + (col&3);
            half8 fh;
            #pragma unroll
            for (int j = 0; j < 8; ++j) {
                const int c = 8 * g + j;
                fh[j] = (c < 21) ? (_Float16)w0[oc * 21 + c] : (_Float16)0.f;
            }
            wf0[mt * 64 + lane] = __builtin_bit_cast(uint4, fh);
        }
        // att logit A-fragment: row = position, k = channel
        {
            half8 fh;
            #pragma unroll
            for (int j = 0; j < 8; ++j)
                fh[j] = (col < 15) ? (_Float16)attw[col * 32 + 8 * g + j]
                                   : (_Float16)0.f;
            ((uint4*)(ws + WFA_OFF))[lane] = __builtin_bit_cast(uint4, fh);
        }
        if (lane < 16)
            ((float*)(ws + ATTB_OFF))[lane] = (lane < 15) ? attb[lane] : 0.f;
        // shift vectors (per g)
        if (col == 0) {
            #pragma unroll
            for (int k = 0; k < 16; ++k) {
                const int H = k >> 3, t = (k >> 2) & 1, r = k & 3;
                const int o = 32*H + 8*g + 4*t + r;
                const float iva = g1[o] * rsqrtf(vr1[o] + 1e-5f);
                sh1[g*16 + k] = bt1[o] + (cb1[o] - mn1[o]) * iva;
            }
            #pragma unroll
            for (int k = 0; k < 8; ++k) {
                const int MT = k >> 2, r = k & 3;
                const int oc = MT*16 + 4*g + r;
                if (oc < 20) {
                    const float iva = g2[oc] * rsqrtf(vr2[oc] + 1e-5f);
                    sh2[g*8 + k] = bt2[oc] + (cb2[oc] - mn2[oc]) * iva;
                } else sh2[g*8 + k] = 0.f;
            }
        }
    } else if (wv < 3) {
        // conv1 fragments, half H = wv-1; chan1 = 32H + 8(col>>2) + 4t + (col&3)
        const int H = wv - 1;
        #pragma unroll
        for (int t = 0; t < 2; ++t) {
            const int o = 32*H + 8*(col>>2) + 4*t + (col&3);
            const float iva = g1[o] * rsqrtf(vr1[o] + 1e-5f);
            #pragma unroll
            for (int s = 0; s < 3; ++s) {
                half8 fh;
                #pragma unroll
                for (int j = 0; j < 8; ++j)
                    fh[j] = (_Float16)(w1[o*96 + g*24 + j*3 + s] * iva);
                wf1[((H*2 + t)*3 + s)*64 + lane] = __builtin_bit_cast(uint4, fh);
            }
        }
    } else {
        // conv2 fragments, bn2 folded, zero for o >= 20
        #pragma unroll
        for (int MT = 0; MT < 2; ++MT) {
            const int o = MT * 16 + col;
            const float iva = (o < 20) ? g2[o] * rsqrtf(vr2[o] + 1e-5f) : 0.f;
            #pragma unroll
            for (int hh = 0; hh < 2; ++hh)
            #pragma unroll
            for (int tap = 0; tap < 3; ++tap) {
                half8 fh;
                #pragma unroll
                for (int j = 0; j < 8; ++j)
                    fh[j] = (o < 20) ? (_Float16)(w2[o*192 + hh*96 + g*24 + j*3 + tap] * iva)
                                     : (_Float16)0.f;
                wf2[((MT*2 + hh)*3 + tap)*64 + lane] = __builtin_bit_cast(uint4, fh);
            }
        }
    }
}

// ---- conv0 via MFMA + logit-MFMA + softmax; h packed f16; y in-place to sxT ----
template<int P0, int NP>
__device__ __forceinline__ void conv0_att(char* sxT, float* lbuf,
        const half8 (&af0)[2], const half8 af_att, const float4 attb4,
        int col, int g, int lane) {
    half8 hq[NP];                      // packed h: channels 8g..8g+7 (permuted rows)
    #pragma unroll
    for (int i = 0; i < NP; ++i) {
        const int p = P0 + i;
        half8 bf = *(const half8*)(sxT + col * Y_BS + p * Y_RS + g * 16);
        const f32x4 z = {0.f, 0.f, 0.f, 0.f};
        f32x4 h0 = __builtin_amdgcn_mfma_f32_16x16x32_f16(af0[0], bf, z, 0, 0, 0);
        f32x4 h1 = __builtin_amdgcn_mfma_f32_16x16x32_f16(af0[1], bf, z, 0, 0, 0);
        uint4 u;
        u.x = pkrtz(h0[0], h0[1]); u.y = pkrtz(h0[2], h0[3]);
        u.z = pkrtz(h1[0], h1[1]); u.w = pkrtz(h1[2], h1[3]);
        hq[i] = __builtin_bit_cast(half8, u);
        // logits for all batches via MFMA: C[row=pos][col=batch], acc-init = attb
        f32x4 al = {attb4.x, attb4.y, attb4.z, attb4.w};
        al = __builtin_amdgcn_mfma_f32_16x16x32_f16(af_att, hq[i], al, 0, 0, 0);
        if (g == (p >> 2)) lbuf[col * 20 + p] = al[p & 3];
    }
    __syncthreads();    // all 15 logits visible; all conv0 x-reads complete
    const float* lb = lbuf + col * 20;
    float4 l0 = *(const float4*)(lb + 0);
    float4 l1 = *(const float4*)(lb + 4);
    float4 l2 = *(const float4*)(lb + 8);
    float4 l3 = *(const float4*)(lb + 12);      // .w garbage, unused
    float lg[15] = {l0.x,l0.y,l0.z,l0.w, l1.x,l1.y,l1.z,l1.w,
                    l2.x,l2.y,l2.z,l2.w, l3.x,l3.y,l3.z};
    float mA = fmaxf(fmaxf(fmaxf(lg[0],lg[1]), fmaxf(lg[2],lg[3])),
                     fmaxf(fmaxf(lg[4],lg[5]), fmaxf(lg[6],lg[7])));
    float mB = fmaxf(fmaxf(fmaxf(lg[8],lg[9]), fmaxf(lg[10],lg[11])),
                     fmaxf(fmaxf(lg[12],lg[13]), lg[14]));
    const float mx = fmaxf(mA, mB);
    float e[15];
    #pragma unroll
    for (int l = 0; l < 15; ++l) e[l] = __expf(lg[l] - mx);
    float sA = ((e[0]+e[1]) + (e[2]+e[3])) + ((e[4]+e[5]) + (e[6]+e[7]));
    float sB = ((e[8]+e[9]) + (e[10]+e[11])) + ((e[12]+e[13]) + e[14]);
    const float inv = 1.f / (sA + sB);
    #pragma unroll
    for (int i = 0; i < NP; ++i) {
        const int p = P0 + i;
        half8 ys = hq[i] * splat8(e[p] * inv);   // v_pk_mul_f16
        // single contiguous write: channels 8g..8g+7 at byte offset 16g
        *(uint4*)(sxT + col * Y_BS + p * Y_RS + 16 * g) =
            __builtin_bit_cast(uint4, ys);
    }
}

// ---- conv1 half-sweep H from prefolded fragments -> frH register B-fragments ----
template<int H, int R0, int NR>
__device__ __forceinline__ void conv1_half(
    const char* __restrict__ yb, half8 (&frH)[NR],
    const int lane, const int g, const char* __restrict__ ws)
{
    const uint4* wf1 = (const uint4*)(ws + WF1_OFF);
    half8 afA[3], afB[3];
    #pragma unroll
    for (int s = 0; s < 3; ++s) {
        afA[s] = __builtin_bit_cast(half8, wf1[((H*2 + 0)*3 + s)*64 + lane]);
        afB[s] = __builtin_bit_cast(half8, wf1[((H*2 + 1)*3 + s)*64 + lane]);
    }
    const float* sh1 = (const float*)(ws + SH1_OFF) + g*16 + H*8;
    float4 shv0 = *(const float4*)(sh1);
    float4 shv1 = *(const float4*)(sh1 + 4);

    half8 y3[3];
    y3[(R0 + 0) % 3] = *(const half8*)(yb + (R0 + 0) * Y_RS + g * 16);
    y3[(R0 + 1) % 3] = *(const half8*)(yb + (R0 + 1) * Y_RS + g * 16);
    #pragma unroll
    for (int i = 0; i < NR; ++i) {
        const int r = R0 + i;
        y3[(r + 2) % 3] = *(const half8*)(yb + (r + 2) * Y_RS + g * 16);
        // acc-init = bn1 shifts
        f32x4 a0 = {shv0.x, shv0.y, shv0.z, shv0.w};
        f32x4 a1 = {shv1.x, shv1.y, shv1.z, shv1.w};
        #pragma unroll
        for (int s = 0; s < 3; ++s) {
            const half8 yy = y3[(r + s) % 3];
            a0 = __builtin_amdgcn_mfma_f32_16x16x32_f16(afA[s], yy, a0, 0,0,0);
            a1 = __builtin_amdgcn_mfma_f32_16x16x32_f16(afB[s], yy, a1, 0,0,0);
        }
        float z0[4], z1[4];
        #pragma unroll
        for (int r2 = 0; r2 < 4; ++r2) {
            z0[r2] = fmaxf(a0[r2], 0.01f * a0[r2]);
            z1[r2] = fmaxf(a1[r2], 0.01f * a1[r2]);
        }
        uint4 u;
        u.x = pkrtz(z0[0], z0[1]); u.y = pkrtz(z0[2], z0[3]);
        u.z = pkrtz(z1[0], z1[1]); u.w = pkrtz(z1[2], z1[3]);
        frH[i] = __builtin_bit_cast(half8, u);
    }
}

// ---- conv2 tile MT from prefolded fragments -> LDS out staging ----
template<int MT, int P0, int NP, int NR>
__device__ __forceinline__ void conv2_tile(
    float* __restrict__ sout, const half8 (&fr0)[NR], const half8 (&fr1)[NR],
    const int col, const int g, const int lane, const char* __restrict__ ws)
{
    const uint4* wf2 = (const uint4*)(ws + WF2_OFF);
    half8 af3[6];
    #pragma unroll
    for (int hh = 0; hh < 2; ++hh)
    #pragma unroll
    for (int tap = 0; tap < 3; ++tap)
        af3[tap*2 + hh] = __builtin_bit_cast(half8, wf2[((MT*2 + hh)*3 + tap)*64 + lane]);
    float4 shv = *(const float4*)((const float*)(ws + SH2_OFF) + g*8 + MT*4);

    #pragma unroll
    for (int pp = 0; pp < NP; ++pp) {
        const int p = P0 + pp;
        f32x4 acc = {shv.x, shv.y, shv.z, shv.w};   // acc-init = bn2 shifts
        #pragma unroll
        for (int s = 0; s < 6; ++s) {
            const half8 bb = (s & 1) ? fr1[pp + (s >> 1)] : fr0[pp + (s >> 1)];
            acc = __builtin_amdgcn_mfma_f32_16x16x32_f16(af3[s], bb, acc, 0,0,0);
        }
        #pragma unroll
        for (int r = 0; r < 4; ++r) {
            const int oc = MT*16 + 4*g + r;
            if (oc < 20) {
                float t0 = fmaxf(acc[r], 0.01f * acc[r]);
                sout[col*OUT_SDW + oc*11 + p] = t0;
            }
        }
    }
}

// ---- conv1 (two half-sweeps) -> fr regs -> conv2 (two tile-sweeps) -> LDS staging ----
template<int R0, int NR, int P0, int NP>
__device__ __forceinline__ void stack23(
    char* __restrict__ sxT, const int col, const int g, const int lane,
    const char* __restrict__ ws)
{
    float* sout = (float*)sxT;
    const char* yb = sxT + col * Y_BS;
    half8 fr0[NR], fr1[NR];
    conv1_half<0, R0, NR>(yb, fr0, lane, g, ws);
    __builtin_amdgcn_sched_barrier(0);    // keep the two halves' af live-ranges separate
    conv1_half<1, R0, NR>(yb, fr1, lane, g, ws);
    __syncthreads();   // all y reads done before out staging overwrites sxT
    conv2_tile<0, P0, NP, NR>(sout, fr0, fr1, col, g, lane, ws);
    __builtin_amdgcn_sched_barrier(0);
    conv2_tile<1, P0, NP, NR>(sout, fr0, fr1, col, g, lane, ws);
}

__global__ __launch_bounds__(THREADS, 2)
void peptide_v19(const float* __restrict__ x,
                 const char*  __restrict__ ws,     // prefolded fragments
                 float* __restrict__ out)          // [B][20][11]
{
    __shared__ __align__(16) char smem[SMEM_BYTES];
    char* sxT = smem;
    float* lbuf = (float*)(smem + LB_OFF);

    const int tid  = threadIdx.x;
    const int lane = tid & 63;
    const int wv   = tid >> 6;
    const int col  = lane & 15;
    const int g    = lane >> 4;

    // ---- quad-gather transpose: 192 tasks = (ch-group 0..2)*(p-quad 0..3)*(batch 0..15)
    {
        const float* xg = x + (size_t)blockIdx.x * (BPB * 315);
        #pragma unroll
        for (int q = 0; q < 2; ++q) {
            const int u = q * THREADS + tid;
            if (u < 192) {
                const int b2 = u & 15;
                const int qd = (u >> 4) & 3;
                const int ch = u >> 6;               // 0,1,2 (wave-uniform)
                const int po = (qd == 3) ? 11 : 4 * qd;
                const float* src = xg + b2 * 315 + po;
                char* dstb = sxT + b2 * Y_BS + ch * 16;
                if (ch < 2) {
                    f32x4 v4[8];
                    #pragma unroll
                    for (int j = 0; j < 8; ++j)
                        v4[j] = *(const f32x4*)(src + (ch * 8 + j) * 15);
                    #pragma unroll
                    for (int e = 0; e < 4; ++e) {
                        if (qd < 3 || e > 0) {
                            const int p = po + e;
                            uint4 d;
                            d.x = pkrtz(v4[0][e], v4[1][e]);
                            d.y = pkrtz(v4[2][e], v4[3][e]);
                            d.z = pkrtz(v4[4][e], v4[5][e]);
                            d.w = pkrtz(v4[6][e], v4[7][e]);
                            *(uint4*)(dstb + p * Y_RS) = d;
                        }
                    }
                } else {
                    f32x4 v4[5];
                    #pragma unroll
                    for (int j = 0; j < 5; ++j)
                        v4[j] = *(const f32x4*)(src + (16 + j) * 15);
                    const uint4 zz = {0u, 0u, 0u, 0u};
                    #pragma unroll
                    for (int e = 0; e < 4; ++e) {
                        if (qd < 3 || e > 0) {
                            const int p = po + e;
                            uint4 d;
                            d.x = pkrtz(v4[0][e], v4[1][e]);
                            d.y = pkrtz(v4[2][e], v4[3][e]);
                            d.z = pkrtz(v4[4][e], 0.f);
                            d.w = 0u;
                            *(uint4*)(dstb + p * Y_RS) = d;        // ch 16..23
                            *(uint4*)(dstb + p * Y_RS + 16) = zz;  // ch 24..31
                        }
                    }
                }
            }
        }
    }

    // fragments from d_ws
    half8 af0[2], af_att;
    float4 attb4;
    {
        const uint4* wf0 = (const uint4*)ws;
        af0[0] = __builtin_bit_cast(half8, wf0[lane]);
        af0[1] = __builtin_bit_cast(half8, wf0[64 + lane]);
        af_att = __builtin_bit_cast(half8, ((const uint4*)(ws + WFA_OFF))[lane]);
        attb4  = *(const float4*)((const float*)(ws + ATTB_OFF) + 4 * g);
    }
    __syncthreads();                      // xT ready

    // ---- conv0 MFMA + logit-MFMA + softmax (y in-place) ----
    if (wv == 0) conv0_att<0, 8>(sxT, lbuf, af0, af_att, attb4, col, g, lane);
    else         conv0_att<8, 7>(sxT, lbuf, af0, af_att, attb4, col, g, lane);
    __syncthreads();                      // y complete (cross-wave rows)

    // ---- conv1 -> regs -> conv2 -> out staging ----
    if (wv == 0) stack23<0, 8, 0, 6>(sxT, col, g, lane, ws);
    else         stack23<6, 7, 6, 5>(sxT, col, g, lane, ws);
    __syncthreads();                      // out staging complete

    // ---- gap-free coalesced copy-out: 16 x 220 dw = one 14080 B span ----
    {
        float* ob = out + (size_t)blockIdx.x * (BPB * 220);
        const float* sf = (const float*)sxT;
        #pragma unroll
        for (int j = 0; j < 7; ++j) {
            const int u = j * THREADS + tid;          // 16B unit
            if (u < 880) {
                f32x4 v = *(const f32x4*)(sf + u * 4);
                *(f32x4*)(ob + u * 4) = v;
            }
        }
    }
}

extern "C" void kernel_launch(void* const* d_in, const int* in_sizes, int n_in,
                              void* d_out, int out_size, void* d_ws, size_t ws_size,
                              hipStream_t stream) {
    const float* x    = (const float*)d_in[0];
    const float* w0   = (const float*)d_in[1];
    const float* attw = (const float*)d_in[2];
    const float* attb = (const float*)d_in[3];
    const float* w1   = (const float*)d_in[4];
    const float* cb1  = (const float*)d_in[5];
    const float* g1   = (const float*)d_in[6];
    const float* bt1  = (const float*)d_in[7];
    const float* mn1  = (const float*)d_in[8];
    const float* vr1  = (const float*)d_in[9];
    const float* w2   = (const float*)d_in[10];
    const float* cb2  = (const float*)d_in[11];
    const float* g2   = (const float*)d_in[12];
    const float* bt2  = (const float*)d_in[13];
    const float* mn2  = (const float*)d_in[14];
    const float* vr2  = (const float*)d_in[15];

    hipLaunchKernelGGL(peptide_prep, dim3(1), dim3(256), 0, stream,
                       w0, attw, attb, w1, cb1, g1, bt1, mn1, vr1,
                       w2, cb2, g2, bt2, mn2, vr2, (char*)d_ws);
    hipLaunchKernelGGL(peptide_v19, dim3(NBLOCKS), dim3(THREADS), 0, stream,
                       x, (const char*)d_ws, (float*)d_out);
}